// Round 3
// baseline (1028.711 us; speedup 1.0000x reference)
//
#include <hip/hip_runtime.h>
#include <hip/hip_bf16.h>
#include <stdint.h>

typedef __attribute__((ext_vector_type(8))) short short8;
typedef __attribute__((ext_vector_type(4))) float f32x4;

#define DEVINL static __device__ __forceinline__

// ---------- helpers ----------
DEVINL unsigned short f2bf(float x) {
  union { float f; unsigned int u; } c; c.f = x;
  unsigned int u = c.u;
  u += 0x7fffu + ((u >> 16) & 1u);   // RNE
  return (unsigned short)(u >> 16);
}

DEVINL float bf2f(unsigned short x) {
  union { unsigned int u; float f; } c; c.u = ((unsigned int)x) << 16;
  return c.f;
}

DEVINL f32x4 mfma16(short8 a, short8 b, f32x4 c) {
  return __builtin_amdgcn_mfma_f32_16x16x32_bf16(a, b, c, 0, 0, 0);
}

DEVINL void gload16(const void* g, void* l) {
  __builtin_amdgcn_global_load_lds((const __attribute__((address_space(1))) void*)g,
                                   (__attribute__((address_space(3))) void*)l, 16, 0, 0);
}

// ---------- problem constants ----------
static constexpr int BB = 2, SS = 2048, HH = 3072;
static constexpr int NH = 24, NKV = 8, HD = 128, NREP = 3;
static constexpr int MM = BB * SS;            // 4096 token rows
static constexpr int KQ = NH * HD;            // 3072
static constexpr int KKV = NKV * HD;          // 1024

// ---------- fp32 -> bf16 convert (optional scale) ----------
__global__ void k_cvt(const float* __restrict__ in, unsigned short* __restrict__ out,
                      int n, float scale) {
  int i = (blockIdx.x * 256 + threadIdx.x) * 4;
  if (i >= n) return;
  float4 v = *reinterpret_cast<const float4*>(in + i);
  ushort4 o;
  o.x = f2bf(v.x * scale); o.y = f2bf(v.y * scale);
  o.z = f2bf(v.z * scale); o.w = f2bf(v.w * scale);
  *reinterpret_cast<ushort4*>(out + i) = o;
}

// ---------- weight transpose + convert: in fp32 [R][C] -> out bf16 [C][R] ----------
__global__ void k_tcvt(const float* __restrict__ in, unsigned short* __restrict__ out,
                       int R, int C) {
  __shared__ float t[32][33];
  int tx = threadIdx.x & 31, ty = threadIdx.x >> 5;   // 32 x 8
  int r0 = blockIdx.y * 32, c0 = blockIdx.x * 32;
#pragma unroll
  for (int i = 0; i < 32; i += 8)
    t[ty + i][tx] = in[(long)(r0 + ty + i) * C + c0 + tx];
  __syncthreads();
#pragma unroll
  for (int i = 0; i < 32; i += 8)
    out[(long)(c0 + ty + i) * R + r0 + tx] = f2bf(t[tx][ty + i]);
}

// ---------- V transpose (bf16): V[b][s][kv*128+d] -> VT[b][kv][d][s] ----------
__global__ void k_vt(const unsigned short* __restrict__ V, unsigned short* __restrict__ VT) {
  __shared__ unsigned short t[32][33];
  int b = blockIdx.z >> 3, kv = blockIdx.z & 7;
  int tx = threadIdx.x & 31, ty = threadIdx.x >> 5;
  int d0 = blockIdx.x * 32, s0 = blockIdx.y * 32;
  const unsigned short* src = V + ((long)b * SS) * KKV + kv * HD;
  unsigned short* dst = VT + (long)(b * NKV + kv) * HD * SS;
#pragma unroll
  for (int i = 0; i < 32; i += 8)
    t[ty + i][tx] = src[(long)(s0 + ty + i) * KKV + d0 + tx];
  __syncthreads();
#pragma unroll
  for (int i = 0; i < 32; i += 8)
    dst[(long)(d0 + ty + i) * SS + s0 + tx] = t[tx][ty + i];
}

// ---------- bf16 GEMM, m97-style: C[M][N] = A[M][K] * Bt[N][K]^T ----------
template <typename OutT>
__global__ __launch_bounds__(256, 2) void k_gemm(const unsigned short* __restrict__ A,
                                                 const unsigned short* __restrict__ Bt,
                                                 OutT* __restrict__ C,
                                                 int M, int N, int K) {
  __shared__ alignas(16) unsigned short As[128 * 64];
  __shared__ alignas(16) unsigned short Bs[128 * 64];
  const int tid = threadIdx.x;
  const int wave = tid >> 6, lane = tid & 63;
  const int l15 = lane & 15, g = lane >> 4;
  const int wr = wave >> 1, wc = wave & 1;
  const long m0 = (long)blockIdx.y * 128, n0 = (long)blockIdx.x * 128;

  f32x4 acc[4][4] = {{{0.f,0.f,0.f,0.f}}};

  for (long k0 = 0; k0 < K; k0 += 64) {
#pragma unroll
    for (int j = 0; j < 4; ++j) {
      int idx = j * 256 + wave * 64 + lane;
      int row = idx >> 3, sub = idx & 7;
      int sc_ = (sub ^ (row & 7)) * 8;               // pre-swizzled global source
      gload16(A  + (m0 + row) * K + k0 + sc_, (char*)As + (j * 4 + wave) * 1024);
      gload16(Bt + (n0 + row) * K + k0 + sc_, (char*)Bs + (j * 4 + wave) * 1024);
    }
    __syncthreads();
#pragma unroll
    for (int ks = 0; ks < 2; ++ks) {
      short8 a[4], b[4];
#pragma unroll
      for (int m = 0; m < 4; ++m) {
        int row = wr * 64 + m * 16 + l15;
        int cb = (ks * 64 + g * 16) ^ ((row & 7) << 4);   // swizzled read
        a[m] = *reinterpret_cast<const short8*>((const char*)As + row * 128 + cb);
      }
#pragma unroll
      for (int n = 0; n < 4; ++n) {
        int row = wc * 64 + n * 16 + l15;
        int cb = (ks * 64 + g * 16) ^ ((row & 7) << 4);
        b[n] = *reinterpret_cast<const short8*>((const char*)Bs + row * 128 + cb);
      }
#pragma unroll
      for (int m = 0; m < 4; ++m)
#pragma unroll
        for (int n = 0; n < 4; ++n)
          acc[m][n] = mfma16(a[m], b[n], acc[m][n]);
    }
    __syncthreads();
  }

#pragma unroll
  for (int m = 0; m < 4; ++m)
#pragma unroll
    for (int n = 0; n < 4; ++n)
#pragma unroll
      for (int r = 0; r < 4; ++r) {
        long row = m0 + wr * 64 + m * 16 + g * 4 + r;
        long col = n0 + wc * 64 + n * 16 + l15;
        float v = acc[m][n][r];
        if constexpr (sizeof(OutT) == 2) C[row * N + col] = f2bf(v);
        else                             C[row * N + col] = v;
      }
}

// ---------- flash attention: 1 wave/block, no barriers, K/V direct from L2 ----------
// grid: 3072 blocks x 64 threads; each wave owns 32 q-rows of one head.
__global__ __launch_bounds__(64, 4) void k_attn(const unsigned short* __restrict__ Q,
                                                const unsigned short* __restrict__ Kb,
                                                const unsigned short* __restrict__ VT,
                                                const unsigned short* __restrict__ Mb,
                                                unsigned short* __restrict__ AO) {
  const int lane = threadIdx.x;
  const int l15 = lane & 15, g = lane >> 4;

  // XCD-chunk swizzle (3072 % 8 == 0, chunk = 384); qtile-inner => same-XCD blocks share kv
  const int bid = blockIdx.x;
  const int id = (bid & 7) * 384 + (bid >> 3);
  const int qtile = id & 63;
  const int rest = id >> 6;
  const int h = rest % NH, b = rest / NH;
  const int kv = h / NREP;
  const int qbase = qtile * 32;

  const unsigned short* Qp = Q + ((long)b * SS + qbase) * KQ + h * HD;
  const unsigned short* Kp = Kb + (long)b * SS * KKV + kv * HD;
  const unsigned short* Vp = VT + (long)(b * NKV + kv) * HD * SS;
  const unsigned short* Mp = Mb + (long)b * SS * SS + (long)qbase * SS;

  // P tile: 32 rows x 128 B, XOR-swizzled (conflict-free b128 reads)
  __shared__ alignas(16) unsigned short Pw[32 * 64];

  const float SC2 = 0.08838834764831845f * 1.4426950408889634f;  // 1/sqrt(128) * log2(e)

  // Q fragments (B-operand): lane (g,l15) holds Q[qh*16+l15][c*32+g*8 ..+7]
  short8 qf[2][4];
#pragma unroll
  for (int qh = 0; qh < 2; ++qh)
#pragma unroll
    for (int c = 0; c < 4; ++c)
      qf[qh][c] = *reinterpret_cast<const short8*>(Qp + (long)(qh * 16 + l15) * KQ + c * 32 + g * 8);

  f32x4 o[2][8] = {{{0.f,0.f,0.f,0.f}}};
  float mrun[2] = {-1e30f, -1e30f}, lrun[2] = {0.f, 0.f};

  for (int kt = 0; kt < SS; kt += 64) {
    // ---- QK^T (swapped): sc[qh][blk] row=key(g*4+r), col=q(l15); K direct from L2 ----
    f32x4 sc[2][4] = {{{0.f,0.f,0.f,0.f}}};
    __builtin_amdgcn_s_setprio(1);
#pragma unroll
    for (int blk = 0; blk < 4; ++blk) {
      short8 kf[4];
      const unsigned short* kr = Kp + (long)(kt + blk * 16 + l15) * KKV + g * 8;
#pragma unroll
      for (int c = 0; c < 4; ++c)
        kf[c] = *reinterpret_cast<const short8*>(kr + c * 32);
#pragma unroll
      for (int c = 0; c < 4; ++c) {
        sc[0][blk] = mfma16(kf[c], qf[0][c], sc[0][blk]);
        sc[1][blk] = mfma16(kf[c], qf[1][c], sc[1][blk]);
      }
    }
    __builtin_amdgcn_s_setprio(0);

    // ---- scale + bf16 mask (pre-scaled by log2e) + tile max ----
    float tmax[2];
#pragma unroll
    for (int qh = 0; qh < 2; ++qh) {
      const unsigned short* mrow = Mp + (long)(qh * 16 + l15) * SS + kt + g * 4;
      float mx = -1e30f;
#pragma unroll
      for (int blk = 0; blk < 4; ++blk) {
        ushort4 mk = *reinterpret_cast<const ushort4*>(mrow + blk * 16);
#pragma unroll
        for (int r = 0; r < 4; ++r) {
          float x = sc[qh][blk][r] * SC2 + bf2f((&mk.x)[r]);
          sc[qh][blk][r] = x;
          mx = fmaxf(mx, x);
        }
      }
      mx = fmaxf(mx, __shfl_xor(mx, 16));
      mx = fmaxf(mx, __shfl_xor(mx, 32));
      tmax[qh] = mx;
    }

    // ---- defer-max rescale (wave-uniform, rarely taken) ----
    if (!__all((tmax[0] <= mrun[0] + 8.f) && (tmax[1] <= mrun[1] + 8.f))) {
#pragma unroll
      for (int qh = 0; qh < 2; ++qh) {
        float mn = fmaxf(mrun[qh], tmax[qh]);
        float corr = __builtin_amdgcn_exp2f(mrun[qh] - mn);
        mrun[qh] = mn;
        lrun[qh] *= corr;
#pragma unroll
        for (int r = 0; r < 4; ++r) {
          float cr = __shfl(corr, g * 4 + r);
#pragma unroll
          for (int db = 0; db < 8; ++db) o[qh][db][r] *= cr;
        }
      }
    }

    // ---- exp2, row-sum, pack P -> LDS (XOR-128 layout) ----
#pragma unroll
    for (int qh = 0; qh < 2; ++qh) {
      float ts = 0.f;
#pragma unroll
      for (int blk = 0; blk < 4; ++blk) {
#pragma unroll
        for (int r = 0; r < 4; ++r) {
          float p = __builtin_amdgcn_exp2f(sc[qh][blk][r] - mrun[qh]);
          sc[qh][blk][r] = p;
          ts += p;
        }
        uint2 pk;
        pk.x = (unsigned int)f2bf(sc[qh][blk][0]) | ((unsigned int)f2bf(sc[qh][blk][1]) << 16);
        pk.y = (unsigned int)f2bf(sc[qh][blk][2]) | ((unsigned int)f2bf(sc[qh][blk][3]) << 16);
        *reinterpret_cast<uint2*>((char*)Pw + (qh * 16 + l15) * 128 +
                                  ((blk * 32 + g * 8) ^ ((l15 & 7) << 4))) = pk;
      }
      ts += __shfl_xor(ts, 16);
      ts += __shfl_xor(ts, 32);
      lrun[qh] += ts;
    }

    // ---- PV: a = P rows(q) from LDS, b = V^T rows(d) direct from L2 ----
    __builtin_amdgcn_s_setprio(1);
#pragma unroll
    for (int ks = 0; ks < 2; ++ks) {
      short8 pa0 = *reinterpret_cast<const short8*>(
          (const char*)Pw + l15 * 128 + ((ks * 64 + g * 16) ^ ((l15 & 7) << 4)));
      short8 pa1 = *reinterpret_cast<const short8*>(
          (const char*)Pw + (16 + l15) * 128 + ((ks * 64 + g * 16) ^ ((l15 & 7) << 4)));
#pragma unroll
      for (int db = 0; db < 8; ++db) {
        short8 vf = *reinterpret_cast<const short8*>(
            Vp + (long)(db * 16 + l15) * SS + kt + ks * 32 + g * 8);
        o[0][db] = mfma16(pa0, vf, o[0][db]);
        o[1][db] = mfma16(pa1, vf, o[1][db]);
      }
    }
    __builtin_amdgcn_s_setprio(0);
  }

  // ---- epilogue: divide by l, store bf16 ----
#pragma unroll
  for (int qh = 0; qh < 2; ++qh) {
#pragma unroll
    for (int r = 0; r < 4; ++r) {
      float lq = __shfl(lrun[qh], g * 4 + r);
      float inv = 1.f / lq;
      long row = qbase + qh * 16 + g * 4 + r;
#pragma unroll
      for (int db = 0; db < 8; ++db)
        AO[((long)b * SS + row) * KQ + h * HD + db * 16 + l15] = f2bf(o[qh][db][r] * inv);
    }
  }
}

// ---------- launch ----------
extern "C" void kernel_launch(void* const* d_in, const int* in_sizes, int n_in,
                              void* d_out, int out_size, void* d_ws, size_t ws_size,
                              hipStream_t stream) {
  const float* hidden = (const float*)d_in[0];
  const float* mask   = (const float*)d_in[1];
  const float* Wq     = (const float*)d_in[2];
  const float* Wk     = (const float*)d_in[3];
  const float* Wv     = (const float*)d_in[4];
  const float* Wo     = (const float*)d_in[5];

  char* ws = (char*)d_ws;
  constexpr long SZ_X   = (long)MM * HH * 2;          // 25.2 MB bf16
  constexpr long SZ_WQT = (long)HH * KQ * 2;          // 18.9 MB
  constexpr long SZ_WKT = (long)HH * KKV * 2;         // 6.3 MB
  constexpr long SZ_QKV = (long)MM * KKV * 2;         // 8.4 MB
  unsigned short* Xb  = (unsigned short*)(ws);
  unsigned short* WqT = (unsigned short*)(ws + SZ_X);
  unsigned short* WkT = (unsigned short*)(ws + SZ_X + SZ_WQT);
  unsigned short* WvT = (unsigned short*)(ws + SZ_X + SZ_WQT + SZ_WKT);
  unsigned short* WoT = (unsigned short*)(ws + SZ_X + SZ_WQT + 2 * SZ_WKT);
  unsigned short* Qb  = (unsigned short*)(ws + SZ_X + 2 * SZ_WQT + 2 * SZ_WKT);
  unsigned short* Kb  = (unsigned short*)(ws + 2 * SZ_X + 2 * SZ_WQT + 2 * SZ_WKT);
  unsigned short* Vb  = (unsigned short*)(ws + 2 * SZ_X + 2 * SZ_WQT + 2 * SZ_WKT + SZ_QKV);
  unsigned short* VTb = (unsigned short*)(ws + 2 * SZ_X + 2 * SZ_WQT + 2 * SZ_WKT + 2 * SZ_QKV);
  unsigned short* AOb = (unsigned short*)(ws + 2 * SZ_X + 2 * SZ_WQT + 2 * SZ_WKT + 3 * SZ_QKV);
  // mask bf16 (pre-scaled by log2e) reuses WqT region (dead after Q projection)
  unsigned short* Mbf = WqT;

  // 1) converts / weight transposes
  k_cvt<<<(MM * HH) / 1024, 256, 0, stream>>>(hidden, Xb, MM * HH, 1.0f);
  k_tcvt<<<dim3(KQ / 32, HH / 32), 256, 0, stream>>>(Wq, WqT, HH, KQ);
  k_tcvt<<<dim3(KKV / 32, HH / 32), 256, 0, stream>>>(Wk, WkT, HH, KKV);
  k_tcvt<<<dim3(KKV / 32, HH / 32), 256, 0, stream>>>(Wv, WvT, HH, KKV);
  k_tcvt<<<dim3(KQ / 32, HH / 32), 256, 0, stream>>>(Wo, WoT, KQ, HH);

  // 2) projections
  k_gemm<unsigned short><<<dim3(KQ / 128, MM / 128), 256, 0, stream>>>(Xb, WqT, Qb, MM, KQ, HH);
  k_gemm<unsigned short><<<dim3(KKV / 128, MM / 128), 256, 0, stream>>>(Xb, WkT, Kb, MM, KKV, HH);
  k_gemm<unsigned short><<<dim3(KKV / 128, MM / 128), 256, 0, stream>>>(Xb, WvT, Vb, MM, KKV, HH);

  // 3) V -> V^T ; mask fp32 -> bf16*log2e (overwrites WqT, now dead)
  k_vt<<<dim3(HD / 32, SS / 32, BB * NKV), 256, 0, stream>>>(Vb, VTb);
  k_cvt<<<(BB * SS * SS) / 1024, 256, 0, stream>>>(mask, Mbf, BB * SS * SS,
                                                   1.4426950408889634f);

  // 4) attention: 3072 one-wave blocks, no barriers
  k_attn<<<64 * NH * BB, 64, 0, stream>>>(Qb, Kb, VTb, Mbf, AOb);

  // 5) output projection -> fp32 d_out
  k_gemm<float><<<dim3(HH / 128, MM / 128), 256, 0, stream>>>(AOb, WoT, (float*)d_out, MM, HH, HH);
}

// Round 4
// 581.356 us; speedup vs baseline: 1.7695x; 1.7695x over previous
//
#include <hip/hip_runtime.h>
#include <hip/hip_bf16.h>
#include <stdint.h>

typedef __attribute__((ext_vector_type(8))) short short8;
typedef __attribute__((ext_vector_type(4))) float f32x4;

#define DEVINL static __device__ __forceinline__

// ---------- helpers ----------
DEVINL unsigned short f2bf(float x) {
  union { float f; unsigned int u; } c; c.f = x;
  unsigned int u = c.u;
  u += 0x7fffu + ((u >> 16) & 1u);   // RNE
  return (unsigned short)(u >> 16);
}

DEVINL float bf2f(unsigned short x) {
  union { unsigned int u; float f; } c; c.u = ((unsigned int)x) << 16;
  return c.f;
}

DEVINL f32x4 mfma16(short8 a, short8 b, f32x4 c) {
  return __builtin_amdgcn_mfma_f32_16x16x32_bf16(a, b, c, 0, 0, 0);
}

DEVINL void gload16(const void* g, void* l) {
  __builtin_amdgcn_global_load_lds((const __attribute__((address_space(1))) void*)g,
                                   (__attribute__((address_space(3))) void*)l, 16, 0, 0);
}

// ---------- problem constants ----------
static constexpr int BB = 2, SS = 2048, HH = 3072;
static constexpr int NH = 24, NKV = 8, HD = 128, NREP = 3;
static constexpr int MM = BB * SS;            // 4096 token rows
static constexpr int KQ = NH * HD;            // 3072
static constexpr int KKV = NKV * HD;          // 1024

// ---------- fp32 -> bf16 convert (optional scale) ----------
__global__ void k_cvt(const float* __restrict__ in, unsigned short* __restrict__ out,
                      int n, float scale) {
  int i = (blockIdx.x * 256 + threadIdx.x) * 4;
  if (i >= n) return;
  float4 v = *reinterpret_cast<const float4*>(in + i);
  ushort4 o;
  o.x = f2bf(v.x * scale); o.y = f2bf(v.y * scale);
  o.z = f2bf(v.z * scale); o.w = f2bf(v.w * scale);
  *reinterpret_cast<ushort4*>(out + i) = o;
}

// ---------- weight transpose + convert: in fp32 [R][C] -> out bf16 [C][R] ----------
__global__ void k_tcvt(const float* __restrict__ in, unsigned short* __restrict__ out,
                       int R, int C) {
  __shared__ float t[32][33];
  int tx = threadIdx.x & 31, ty = threadIdx.x >> 5;   // 32 x 8
  int r0 = blockIdx.y * 32, c0 = blockIdx.x * 32;
#pragma unroll
  for (int i = 0; i < 32; i += 8)
    t[ty + i][tx] = in[(long)(r0 + ty + i) * C + c0 + tx];
  __syncthreads();
#pragma unroll
  for (int i = 0; i < 32; i += 8)
    out[(long)(c0 + ty + i) * R + r0 + tx] = f2bf(t[tx][ty + i]);
}

// ---------- V transpose (bf16): V[b][s][kv*128+d] -> VT[b][kv][d][s] ----------
__global__ void k_vt(const unsigned short* __restrict__ V, unsigned short* __restrict__ VT) {
  __shared__ unsigned short t[32][33];
  int b = blockIdx.z >> 3, kv = blockIdx.z & 7;
  int tx = threadIdx.x & 31, ty = threadIdx.x >> 5;
  int d0 = blockIdx.x * 32, s0 = blockIdx.y * 32;
  const unsigned short* src = V + ((long)b * SS) * KKV + kv * HD;
  unsigned short* dst = VT + (long)(b * NKV + kv) * HD * SS;
#pragma unroll
  for (int i = 0; i < 32; i += 8)
    t[ty + i][tx] = src[(long)(s0 + ty + i) * KKV + d0 + tx];
  __syncthreads();
#pragma unroll
  for (int i = 0; i < 32; i += 8)
    dst[(long)(d0 + ty + i) * SS + s0 + tx] = t[tx][ty + i];
}

// ---------- bf16 GEMM, m97-style: C[M][N] = A[M][K] * Bt[N][K]^T ----------
template <typename OutT>
__global__ __launch_bounds__(256, 2) void k_gemm(const unsigned short* __restrict__ A,
                                                 const unsigned short* __restrict__ Bt,
                                                 OutT* __restrict__ C,
                                                 int M, int N, int K) {
  __shared__ alignas(16) unsigned short As[128 * 64];
  __shared__ alignas(16) unsigned short Bs[128 * 64];
  const int tid = threadIdx.x;
  const int wave = tid >> 6, lane = tid & 63;
  const int l15 = lane & 15, g = lane >> 4;
  const int wr = wave >> 1, wc = wave & 1;
  const long m0 = (long)blockIdx.y * 128, n0 = (long)blockIdx.x * 128;

  f32x4 acc[4][4] = {{{0.f,0.f,0.f,0.f}}};

  for (long k0 = 0; k0 < K; k0 += 64) {
#pragma unroll
    for (int j = 0; j < 4; ++j) {
      int idx = j * 256 + wave * 64 + lane;
      int row = idx >> 3, sub = idx & 7;
      int sc_ = (sub ^ (row & 7)) * 8;               // pre-swizzled global source
      gload16(A  + (m0 + row) * K + k0 + sc_, (char*)As + (j * 4 + wave) * 1024);
      gload16(Bt + (n0 + row) * K + k0 + sc_, (char*)Bs + (j * 4 + wave) * 1024);
    }
    __syncthreads();
#pragma unroll
    for (int ks = 0; ks < 2; ++ks) {
      short8 a[4], b[4];
#pragma unroll
      for (int m = 0; m < 4; ++m) {
        int row = wr * 64 + m * 16 + l15;
        int cb = (ks * 64 + g * 16) ^ ((row & 7) << 4);   // swizzled read
        a[m] = *reinterpret_cast<const short8*>((const char*)As + row * 128 + cb);
      }
#pragma unroll
      for (int n = 0; n < 4; ++n) {
        int row = wc * 64 + n * 16 + l15;
        int cb = (ks * 64 + g * 16) ^ ((row & 7) << 4);
        b[n] = *reinterpret_cast<const short8*>((const char*)Bs + row * 128 + cb);
      }
#pragma unroll
      for (int m = 0; m < 4; ++m)
#pragma unroll
        for (int n = 0; n < 4; ++n)
          acc[m][n] = mfma16(a[m], b[n], acc[m][n]);
    }
    __syncthreads();
  }

#pragma unroll
  for (int m = 0; m < 4; ++m)
#pragma unroll
    for (int n = 0; n < 4; ++n)
#pragma unroll
      for (int r = 0; r < 4; ++r) {
        long row = m0 + wr * 64 + m * 16 + g * 4 + r;
        long col = n0 + wc * 64 + n * 16 + l15;
        float v = acc[m][n][r];
        if constexpr (sizeof(OutT) == 2) C[row * N + col] = f2bf(v);
        else                             C[row * N + col] = v;
      }
}

// ---------- flash attention: 4 waves, K AND V^T staged in LDS (dbuf) ----------
// grid: 768 blocks x 256; wave w owns q rows [qtile*128 + w*32, +32)
__global__ __launch_bounds__(256, 2) void k_attn(const unsigned short* __restrict__ Q,
                                                 const unsigned short* __restrict__ Kb,
                                                 const unsigned short* __restrict__ VT,
                                                 const unsigned short* __restrict__ Mb,
                                                 unsigned short* __restrict__ AO) {
  const int tid = threadIdx.x;
  const int wave = tid >> 6, lane = tid & 63;
  const int l15 = lane & 15, g = lane >> 4;

  // XCD-chunk swizzle: 768 % 8 == 0, chunk 96; qtile-inner => same-XCD shares (b,kv)
  const int bid = blockIdx.x;
  const int id = (bid & 7) * 96 + (bid >> 3);
  const int qt = id & 15;
  const int h  = (id >> 4) % NH;
  const int b  = id / (16 * NH);
  const int kv = h / NREP;
  const int qbase = qt * 128 + wave * 32;

  const unsigned short* Qp = Q + ((long)b * SS + qbase) * KQ + h * HD;
  const unsigned short* Kp = Kb + (long)b * SS * KKV + kv * HD;
  const unsigned short* Vp = VT + (long)(b * NKV + kv) * HD * SS;
  const unsigned short* Mp = Mb + (long)b * SS * SS + (long)qbase * SS;

  __shared__ alignas(16) unsigned short Ks[2][64 * 128];    // 2 x 16 KB
  __shared__ alignas(16) unsigned short Vs[2][128 * 64];    // 2 x 16 KB
  __shared__ alignas(16) unsigned short Pl[4][32 * 64];     // 4 x 4 KB, XOR-128
  unsigned short* Pw = Pl[wave];

  const float SC2 = 0.08838834764831845f * 1.4426950408889634f;  // 1/sqrt(128)*log2e

  // Q fragments (B-operand): lane (g,l15) holds Q[qh*16+l15][c*32+g*8 ..+7]
  short8 qf[2][4];
#pragma unroll
  for (int qh = 0; qh < 2; ++qh)
#pragma unroll
    for (int c = 0; c < 4; ++c)
      qf[qh][c] = *reinterpret_cast<const short8*>(Qp + (long)(qh * 16 + l15) * KQ + c * 32 + g * 8);

  f32x4 o[2][8] = {{{0.f,0.f,0.f,0.f}}};
  float mrun[2] = {-1e30f, -1e30f}, lrun[2] = {0.f, 0.f};

  // stage K tile [64 rows][16 subs x 16B] + V^T tile [128 rows][8 subs x 16B]
  auto stage = [&](int buf, int kt) {
#pragma unroll
    for (int j = 0; j < 4; ++j) {
      int idx = j * 256 + wave * 64 + lane;
      {   // K: row = idx>>4, sub = idx&15; involution sub' = (s&8)|((s^row)&7)
        int row = idx >> 4, sub = idx & 15;
        int ssub = (sub & 8) | ((sub ^ row) & 7);
        gload16(Kp + (long)(kt + row) * KKV + ssub * 8,
                (char*)Ks[buf] + (j * 256 + wave * 64) * 16);
      }
      {   // V: row(d) = idx>>3, sub = idx&7; involution sub' = sub^(row&7)
        int row = idx >> 3, sub = idx & 7;
        int ssub = sub ^ (row & 7);
        gload16(Vp + (long)row * SS + kt + ssub * 8,
                (char*)Vs[buf] + (j * 256 + wave * 64) * 16);
      }
    }
  };

  stage(0, 0);
  __syncthreads();

  for (int t = 0; t < SS / 64; ++t) {
    const int kt = t * 64;
    if (t < SS / 64 - 1) stage((t + 1) & 1, kt + 64);
    const char* Kt = (const char*)Ks[t & 1];
    const char* Vt = (const char*)Vs[t & 1];

    // ---- QK^T (swapped): sc[qh][blk], D row=key(g*4+r), col=q(l15) ----
    f32x4 sc[2][4] = {{{0.f,0.f,0.f,0.f}}};
    __builtin_amdgcn_s_setprio(1);
#pragma unroll
    for (int blk = 0; blk < 4; ++blk) {
      short8 kf[4];
      const int row = blk * 16 + l15;
#pragma unroll
      for (int c = 0; c < 4; ++c) {
        int s = c * 4 + g;
        int ssub = (s & 8) | ((s ^ row) & 7);
        kf[c] = *reinterpret_cast<const short8*>(Kt + row * 256 + ssub * 16);
      }
#pragma unroll
      for (int c = 0; c < 4; ++c) {
        sc[0][blk] = mfma16(kf[c], qf[0][c], sc[0][blk]);
        sc[1][blk] = mfma16(kf[c], qf[1][c], sc[1][blk]);
      }
    }
    __builtin_amdgcn_s_setprio(0);

    // ---- scale + bf16 mask (pre-scaled by log2e) + tile max ----
    float tmax[2];
#pragma unroll
    for (int qh = 0; qh < 2; ++qh) {
      const unsigned short* mrow = Mp + (long)(qh * 16 + l15) * SS + kt + g * 4;
      float mx = -1e30f;
#pragma unroll
      for (int blk = 0; blk < 4; ++blk) {
        ushort4 mk = *reinterpret_cast<const ushort4*>(mrow + blk * 16);
#pragma unroll
        for (int r = 0; r < 4; ++r) {
          float x = sc[qh][blk][r] * SC2 + bf2f((&mk.x)[r]);
          sc[qh][blk][r] = x;
          mx = fmaxf(mx, x);
        }
      }
      mx = fmaxf(mx, __shfl_xor(mx, 16));
      mx = fmaxf(mx, __shfl_xor(mx, 32));
      tmax[qh] = mx;
    }

    // ---- defer-max rescale (wave-uniform, rarely taken) ----
    if (!__all((tmax[0] <= mrun[0] + 8.f) && (tmax[1] <= mrun[1] + 8.f))) {
#pragma unroll
      for (int qh = 0; qh < 2; ++qh) {
        float mn = fmaxf(mrun[qh], tmax[qh]);
        float corr = __builtin_amdgcn_exp2f(mrun[qh] - mn);
        mrun[qh] = mn;
        lrun[qh] *= corr;
#pragma unroll
        for (int r = 0; r < 4; ++r) {
          float cr = __shfl(corr, g * 4 + r);
#pragma unroll
          for (int db = 0; db < 8; ++db) o[qh][db][r] *= cr;
        }
      }
    }

    // ---- exp2, row-sum, pack P -> LDS (XOR-128 layout) ----
#pragma unroll
    for (int qh = 0; qh < 2; ++qh) {
      float ts = 0.f;
#pragma unroll
      for (int blk = 0; blk < 4; ++blk) {
#pragma unroll
        for (int r = 0; r < 4; ++r) {
          float p = __builtin_amdgcn_exp2f(sc[qh][blk][r] - mrun[qh]);
          sc[qh][blk][r] = p;
          ts += p;
        }
        uint2 pk;
        pk.x = (unsigned int)f2bf(sc[qh][blk][0]) | ((unsigned int)f2bf(sc[qh][blk][1]) << 16);
        pk.y = (unsigned int)f2bf(sc[qh][blk][2]) | ((unsigned int)f2bf(sc[qh][blk][3]) << 16);
        *reinterpret_cast<uint2*>((char*)Pw + (qh * 16 + l15) * 128 +
                                  ((blk * 32 + g * 8) ^ ((l15 & 7) << 4))) = pk;
      }
      ts += __shfl_xor(ts, 16);
      ts += __shfl_xor(ts, 32);
      lrun[qh] += ts;
    }

    // ---- PV: a = P rows(q) from LDS, b = V^T rows(d) from LDS ----
    __builtin_amdgcn_s_setprio(1);
#pragma unroll
    for (int ks = 0; ks < 2; ++ks) {
      short8 pa0 = *reinterpret_cast<const short8*>(
          (const char*)Pw + l15 * 128 + ((ks * 64 + g * 16) ^ ((l15 & 7) << 4)));
      short8 pa1 = *reinterpret_cast<const short8*>(
          (const char*)Pw + (16 + l15) * 128 + ((ks * 64 + g * 16) ^ ((l15 & 7) << 4)));
#pragma unroll
      for (int db = 0; db < 8; ++db) {
        const int vrow = db * 16 + l15;
        int ssub = (ks * 4 + g) ^ (vrow & 7);
        short8 vf = *reinterpret_cast<const short8*>(Vt + vrow * 128 + ssub * 16);
        o[0][db] = mfma16(pa0, vf, o[0][db]);
        o[1][db] = mfma16(pa1, vf, o[1][db]);
      }
    }
    __builtin_amdgcn_s_setprio(0);

    __syncthreads();   // drains staging (vmcnt) + P reads; flip buffers
  }

  // ---- epilogue: divide by l, store bf16 ----
#pragma unroll
  for (int qh = 0; qh < 2; ++qh) {
#pragma unroll
    for (int r = 0; r < 4; ++r) {
      float lq = __shfl(lrun[qh], g * 4 + r);
      float inv = 1.f / lq;
      long row = qbase + qh * 16 + g * 4 + r;
#pragma unroll
      for (int db = 0; db < 8; ++db)
        AO[((long)b * SS + row) * KQ + h * HD + db * 16 + l15] = f2bf(o[qh][db][r] * inv);
    }
  }
}

// ---------- launch ----------
extern "C" void kernel_launch(void* const* d_in, const int* in_sizes, int n_in,
                              void* d_out, int out_size, void* d_ws, size_t ws_size,
                              hipStream_t stream) {
  const float* hidden = (const float*)d_in[0];
  const float* mask   = (const float*)d_in[1];
  const float* Wq     = (const float*)d_in[2];
  const float* Wk     = (const float*)d_in[3];
  const float* Wv     = (const float*)d_in[4];
  const float* Wo     = (const float*)d_in[5];

  char* ws = (char*)d_ws;
  constexpr long SZ_X   = (long)MM * HH * 2;          // 25.2 MB bf16
  constexpr long SZ_WQT = (long)HH * KQ * 2;          // 18.9 MB
  constexpr long SZ_WKT = (long)HH * KKV * 2;         // 6.3 MB
  constexpr long SZ_QKV = (long)MM * KKV * 2;         // 8.4 MB
  unsigned short* Xb  = (unsigned short*)(ws);
  unsigned short* WqT = (unsigned short*)(ws + SZ_X);
  unsigned short* WkT = (unsigned short*)(ws + SZ_X + SZ_WQT);
  unsigned short* WvT = (unsigned short*)(ws + SZ_X + SZ_WQT + SZ_WKT);
  unsigned short* WoT = (unsigned short*)(ws + SZ_X + SZ_WQT + 2 * SZ_WKT);
  unsigned short* Qb  = (unsigned short*)(ws + SZ_X + 2 * SZ_WQT + 2 * SZ_WKT);
  unsigned short* Kb  = (unsigned short*)(ws + 2 * SZ_X + 2 * SZ_WQT + 2 * SZ_WKT);
  unsigned short* Vb  = (unsigned short*)(ws + 2 * SZ_X + 2 * SZ_WQT + 2 * SZ_WKT + SZ_QKV);
  unsigned short* VTb = (unsigned short*)(ws + 2 * SZ_X + 2 * SZ_WQT + 2 * SZ_WKT + 2 * SZ_QKV);
  unsigned short* AOb = (unsigned short*)(ws + 2 * SZ_X + 2 * SZ_WQT + 2 * SZ_WKT + 3 * SZ_QKV);
  // mask bf16 (pre-scaled by log2e) reuses WqT region (dead after Q projection)
  unsigned short* Mbf = WqT;

  // 1) converts / weight transposes
  k_cvt<<<(MM * HH) / 1024, 256, 0, stream>>>(hidden, Xb, MM * HH, 1.0f);
  k_tcvt<<<dim3(KQ / 32, HH / 32), 256, 0, stream>>>(Wq, WqT, HH, KQ);
  k_tcvt<<<dim3(KKV / 32, HH / 32), 256, 0, stream>>>(Wk, WkT, HH, KKV);
  k_tcvt<<<dim3(KKV / 32, HH / 32), 256, 0, stream>>>(Wv, WvT, HH, KKV);
  k_tcvt<<<dim3(KQ / 32, HH / 32), 256, 0, stream>>>(Wo, WoT, KQ, HH);

  // 2) projections
  k_gemm<unsigned short><<<dim3(KQ / 128, MM / 128), 256, 0, stream>>>(Xb, WqT, Qb, MM, KQ, HH);
  k_gemm<unsigned short><<<dim3(KKV / 128, MM / 128), 256, 0, stream>>>(Xb, WkT, Kb, MM, KKV, HH);
  k_gemm<unsigned short><<<dim3(KKV / 128, MM / 128), 256, 0, stream>>>(Xb, WvT, Vb, MM, KKV, HH);

  // 3) V -> V^T ; mask fp32 -> bf16*log2e (overwrites WqT, now dead)
  k_vt<<<dim3(HD / 32, SS / 32, BB * NKV), 256, 0, stream>>>(Vb, VTb);
  k_cvt<<<(BB * SS * SS) / 1024, 256, 0, stream>>>(mask, Mbf, BB * SS * SS,
                                                   1.4426950408889634f);

  // 4) attention: 768 blocks x 4 waves, K+V LDS-staged double-buffered
  k_attn<<<16 * NH * BB, 256, 0, stream>>>(Qb, Kb, VTb, Mbf, AOb);

  // 5) output projection -> fp32 d_out
  k_gemm<float><<<dim3(HH / 128, MM / 128), 256, 0, stream>>>(AOb, WoT, (float*)d_out, MM, HH, HH);
}

// Round 5
// 539.391 us; speedup vs baseline: 1.9072x; 1.0778x over previous
//
#include <hip/hip_runtime.h>
#include <hip/hip_bf16.h>
#include <stdint.h>

typedef __attribute__((ext_vector_type(8))) short short8;
typedef __attribute__((ext_vector_type(4))) float f32x4;
typedef __attribute__((ext_vector_type(16))) float f32x16;

#define DEVINL static __device__ __forceinline__

// ---------- helpers ----------
DEVINL unsigned short f2bf(float x) {
  union { float f; unsigned int u; } c; c.f = x;
  unsigned int u = c.u;
  u += 0x7fffu + ((u >> 16) & 1u);   // RNE
  return (unsigned short)(u >> 16);
}

DEVINL float bf2f(unsigned short x) {
  union { unsigned int u; float f; } c; c.u = ((unsigned int)x) << 16;
  return c.f;
}

DEVINL f32x4 mfma16(short8 a, short8 b, f32x4 c) {
  return __builtin_amdgcn_mfma_f32_16x16x32_bf16(a, b, c, 0, 0, 0);
}

DEVINL f32x16 mfma32(short8 a, short8 b, f32x16 c) {
  return __builtin_amdgcn_mfma_f32_32x32x16_bf16(a, b, c, 0, 0, 0);
}

DEVINL unsigned int cvtpk(float lo, float hi_) {
  unsigned int r;
  asm("v_cvt_pk_bf16_f32 %0, %1, %2" : "=v"(r) : "v"(lo), "v"(hi_));
  return r;
}

DEVINL void pl32swap(unsigned int& a, unsigned int& b) {
  asm("v_permlane32_swap_b32 %0, %1" : "+v"(a), "+v"(b));
}

DEVINL void gload16(const void* g, void* l) {
  __builtin_amdgcn_global_load_lds((const __attribute__((address_space(1))) void*)g,
                                   (__attribute__((address_space(3))) void*)l, 16, 0, 0);
}

// ---------- problem constants ----------
static constexpr int BB = 2, SS = 2048, HH = 3072;
static constexpr int NH = 24, NKV = 8, HD = 128, NREP = 3;
static constexpr int MM = BB * SS;            // 4096 token rows
static constexpr int KQ = NH * HD;            // 3072
static constexpr int KKV = NKV * HD;          // 1024

// ---------- fp32 -> bf16 convert (optional scale) ----------
__global__ void k_cvt(const float* __restrict__ in, unsigned short* __restrict__ out,
                      int n, float scale) {
  int i = (blockIdx.x * 256 + threadIdx.x) * 4;
  if (i >= n) return;
  float4 v = *reinterpret_cast<const float4*>(in + i);
  ushort4 o;
  o.x = f2bf(v.x * scale); o.y = f2bf(v.y * scale);
  o.z = f2bf(v.z * scale); o.w = f2bf(v.w * scale);
  *reinterpret_cast<ushort4*>(out + i) = o;
}

// ---------- weight transpose + convert: in fp32 [R][C] -> out bf16 [C][R] ----------
__global__ void k_tcvt(const float* __restrict__ in, unsigned short* __restrict__ out,
                       int R, int C) {
  __shared__ float t[32][33];
  int tx = threadIdx.x & 31, ty = threadIdx.x >> 5;   // 32 x 8
  int r0 = blockIdx.y * 32, c0 = blockIdx.x * 32;
#pragma unroll
  for (int i = 0; i < 32; i += 8)
    t[ty + i][tx] = in[(long)(r0 + ty + i) * C + c0 + tx];
  __syncthreads();
#pragma unroll
  for (int i = 0; i < 32; i += 8)
    out[(long)(c0 + ty + i) * R + r0 + tx] = f2bf(t[tx][ty + i]);
}

// ---------- V transpose (bf16): V[b][s][kv*128+d] -> VT[b][kv][d][s] ----------
__global__ void k_vt(const unsigned short* __restrict__ V, unsigned short* __restrict__ VT) {
  __shared__ unsigned short t[32][33];
  int b = blockIdx.z >> 3, kv = blockIdx.z & 7;
  int tx = threadIdx.x & 31, ty = threadIdx.x >> 5;
  int d0 = blockIdx.x * 32, s0 = blockIdx.y * 32;
  const unsigned short* src = V + ((long)b * SS) * KKV + kv * HD;
  unsigned short* dst = VT + (long)(b * NKV + kv) * HD * SS;
#pragma unroll
  for (int i = 0; i < 32; i += 8)
    t[ty + i][tx] = src[(long)(s0 + ty + i) * KKV + d0 + tx];
  __syncthreads();
#pragma unroll
  for (int i = 0; i < 32; i += 8)
    dst[(long)(d0 + ty + i) * SS + s0 + tx] = t[tx][ty + i];
}

// ---------- bf16 GEMM, m97-style: C[M][N] = A[M][K] * Bt[N][K]^T ----------
template <typename OutT>
__global__ __launch_bounds__(256, 2) void k_gemm(const unsigned short* __restrict__ A,
                                                 const unsigned short* __restrict__ Bt,
                                                 OutT* __restrict__ C,
                                                 int M, int N, int K) {
  __shared__ alignas(16) unsigned short As[128 * 64];
  __shared__ alignas(16) unsigned short Bs[128 * 64];
  const int tid = threadIdx.x;
  const int wave = tid >> 6, lane = tid & 63;
  const int l15 = lane & 15, g = lane >> 4;
  const int wr = wave >> 1, wc = wave & 1;
  const long m0 = (long)blockIdx.y * 128, n0 = (long)blockIdx.x * 128;

  f32x4 acc[4][4] = {{{0.f,0.f,0.f,0.f}}};

  for (long k0 = 0; k0 < K; k0 += 64) {
#pragma unroll
    for (int j = 0; j < 4; ++j) {
      int idx = j * 256 + wave * 64 + lane;
      int row = idx >> 3, sub = idx & 7;
      int sc_ = (sub ^ (row & 7)) * 8;               // pre-swizzled global source
      gload16(A  + (m0 + row) * K + k0 + sc_, (char*)As + (j * 4 + wave) * 1024);
      gload16(Bt + (n0 + row) * K + k0 + sc_, (char*)Bs + (j * 4 + wave) * 1024);
    }
    __syncthreads();
#pragma unroll
    for (int ks = 0; ks < 2; ++ks) {
      short8 a[4], b[4];
#pragma unroll
      for (int m = 0; m < 4; ++m) {
        int row = wr * 64 + m * 16 + l15;
        int cb = (ks * 64 + g * 16) ^ ((row & 7) << 4);   // swizzled read
        a[m] = *reinterpret_cast<const short8*>((const char*)As + row * 128 + cb);
      }
#pragma unroll
      for (int n = 0; n < 4; ++n) {
        int row = wc * 64 + n * 16 + l15;
        int cb = (ks * 64 + g * 16) ^ ((row & 7) << 4);
        b[n] = *reinterpret_cast<const short8*>((const char*)Bs + row * 128 + cb);
      }
#pragma unroll
      for (int m = 0; m < 4; ++m)
#pragma unroll
        for (int n = 0; n < 4; ++n)
          acc[m][n] = mfma16(a[m], b[n], acc[m][n]);
    }
    __syncthreads();
  }

#pragma unroll
  for (int m = 0; m < 4; ++m)
#pragma unroll
    for (int n = 0; n < 4; ++n)
#pragma unroll
      for (int r = 0; r < 4; ++r) {
        long row = m0 + wr * 64 + m * 16 + g * 4 + r;
        long col = n0 + wc * 64 + n * 16 + l15;
        float v = acc[m][n][r];
        if constexpr (sizeof(OutT) == 2) C[row * N + col] = f2bf(v);
        else                             C[row * N + col] = v;
      }
}

// ---------- flash attention: 32x32 MFMA, in-register softmax + P (no P-LDS) ----------
// 4 waves x 32 q-rows; K dbuf LDS, V single-buffered; grid 768 = 3/CU exactly.
__global__ __launch_bounds__(256, 3) void k_attn(const unsigned short* __restrict__ Q,
                                                 const unsigned short* __restrict__ Kb,
                                                 const unsigned short* __restrict__ VT,
                                                 const unsigned short* __restrict__ Mb,
                                                 unsigned short* __restrict__ AO) {
  const int tid = threadIdx.x;
  const int wave = tid >> 6, lane = tid & 63;
  const int l31 = lane & 31, hi = lane >> 5;

  // XCD-chunk swizzle: 768 % 8 == 0, chunk 96; qtile-inner => same-XCD shares (b,kv)
  const int bid = blockIdx.x;
  const int id = (bid & 7) * 96 + (bid >> 3);
  const int qt = id & 15;
  const int h  = (id >> 4) % NH;
  const int b  = id / (16 * NH);
  const int kv = h / NREP;
  const int qb = qt * 128 + wave * 32;

  const unsigned short* Qp = Q + ((long)b * SS + qb) * KQ + h * HD;
  const unsigned short* Kp = Kb + (long)b * SS * KKV + kv * HD;
  const unsigned short* Vp = VT + (long)(b * NKV + kv) * HD * SS;
  const unsigned short* Mp = Mb + (long)b * SS * SS + (long)(qb + l31) * SS;  // per-lane q-row

  __shared__ alignas(16) unsigned short Ks[2][64 * 128];   // 2 x 16 KB (dbuf)
  __shared__ alignas(16) unsigned short Vs[128 * 64];      // 16 KB (single)

  const float SC2 = 0.08838834764831845f * 1.4426950408889634f;  // 1/sqrt(128)*log2e

  // Q fragments (B-operand of 32x32x16): lane (l31,hi) holds Q[l31][c*16+hi*8 ..+7]
  short8 qf[8];
#pragma unroll
  for (int c = 0; c < 8; ++c)
    qf[c] = *reinterpret_cast<const short8*>(Qp + (long)l31 * KQ + c * 16 + hi * 8);

  f32x16 o[4];
#pragma unroll
  for (int dc = 0; dc < 4; ++dc)
#pragma unroll
    for (int r = 0; r < 16; ++r) o[dc][r] = 0.f;
  float mrun = -3e38f, lrun = 0.f;

  // K staging: [64 rows][16 slots x 16B], involution slot' = (s&8)|((s^row)&7)
  auto stageK = [&](int buf, int kt) {
#pragma unroll
    for (int j = 0; j < 4; ++j) {
      int idx = j * 256 + wave * 64 + lane;
      int row = idx >> 4, s = idx & 15;
      int ss = (s & 8) | ((s ^ row) & 7);
      gload16(Kp + (long)(kt + row) * KKV + ss * 8,
              (char*)Ks[buf] + (j * 4 + wave) * 1024);
    }
  };
  // V staging: [128 rows][8 slots x 16B], involution slot' = s^(row&7)
  auto stageV = [&](int kt) {
#pragma unroll
    for (int j = 0; j < 4; ++j) {
      int idx = j * 256 + wave * 64 + lane;
      int row = idx >> 3, s = idx & 7;
      int ss = s ^ (row & 7);
      gload16(Vp + (long)row * SS + kt + ss * 8,
              (char*)Vs + (j * 4 + wave) * 1024);
    }
  };

  stageK(0, 0);
  __syncthreads();

  for (int t = 0; t < SS / 64; ++t) {
    const int kt = t * 64;
    stageV(kt);                                   // Vs free (PV(t-1) done at end barrier)
    if (t < SS / 64 - 1) stageK((t + 1) & 1, kt + 64);
    const char* Kt = (const char*)Ks[t & 1];

    // ---- QK^T swapped: sc[sb] = K(sb)·Q^T ; D: row=key crow(r,hi), col=q l31 ----
    f32x16 sc0, sc1;
#pragma unroll
    for (int r = 0; r < 16; ++r) { sc0[r] = 0.f; sc1[r] = 0.f; }
    __builtin_amdgcn_s_setprio(1);
#pragma unroll
    for (int sb = 0; sb < 2; ++sb) {
      const int row = sb * 32 + l31;
#pragma unroll
      for (int ch = 0; ch < 2; ++ch) {
        short8 kf[4];
#pragma unroll
        for (int cc = 0; cc < 4; ++cc) {
          int c = ch * 4 + cc;
          int s = c * 2 + hi;
          int ss = (s & 8) | ((s ^ (row & 7)) & 7);
          kf[cc] = *reinterpret_cast<const short8*>(Kt + row * 256 + ss * 16);
        }
#pragma unroll
        for (int cc = 0; cc < 4; ++cc) {
          if (sb == 0) sc0 = mfma32(kf[cc], qf[ch * 4 + cc], sc0);
          else         sc1 = mfma32(kf[cc], qf[ch * 4 + cc], sc1);
        }
      }
    }
    __builtin_amdgcn_s_setprio(0);

    // ---- scale + mask + tile max (lane owns q-row l31; keys crow(r,hi)+32sb) ----
    float tm = -3e38f;
#pragma unroll
    for (int sb = 0; sb < 2; ++sb) {
#pragma unroll
      for (int u = 0; u < 4; ++u) {
        ushort4 mk = *reinterpret_cast<const ushort4*>(Mp + kt + sb * 32 + u * 8 + hi * 4);
#pragma unroll
        for (int e = 0; e < 4; ++e) {
          int r = u * 4 + e;
          float x = (sb ? sc1[r] : sc0[r]) * SC2 + bf2f((&mk.x)[e]);
          if (sb) sc1[r] = x; else sc0[r] = x;
          tm = fmaxf(tm, x);
        }
      }
    }
    tm = fmaxf(tm, __shfl_xor(tm, 32));

    // ---- defer-max rescale (wave-uniform, rarely taken) ----
    if (!__all(tm <= mrun + 8.f)) {
      float mn = fmaxf(mrun, tm);
      float corr = __builtin_amdgcn_exp2f(mrun - mn);
      mrun = mn;
      lrun *= corr;
#pragma unroll
      for (int r = 0; r < 16; ++r) {
        int qrow = (r & 3) + 8 * (r >> 2) + 4 * hi;
        float cr = __shfl(corr, qrow);
#pragma unroll
        for (int dc = 0; dc < 4; ++dc) o[dc][r] *= cr;
      }
    }

    // ---- exp2 + row-sum (in-register) ----
    float ts = 0.f;
#pragma unroll
    for (int r = 0; r < 16; ++r) {
      float p0 = __builtin_amdgcn_exp2f(sc0[r] - mrun);
      float p1 = __builtin_amdgcn_exp2f(sc1[r] - mrun);
      sc0[r] = p0; sc1[r] = p1;
      ts += p0 + p1;
    }
    ts += __shfl_xor(ts, 32);
    lrun += ts;

    __syncthreads();   // drains V(t)/K(t+1) staging (vmcnt0) before PV reads Vs

    // ---- PV: pa[ks] built in-register (cvt_pk + permlane32_swap), V from LDS ----
    __builtin_amdgcn_s_setprio(1);
#pragma unroll
    for (int ks = 0; ks < 4; ++ks) {
      const int R = 8 * (ks & 1);
      unsigned int A0, A1, B0, B1;
      if (ks < 2) {
        A0 = cvtpk(sc0[R + 0], sc0[R + 1]); A1 = cvtpk(sc0[R + 2], sc0[R + 3]);
        B0 = cvtpk(sc0[R + 4], sc0[R + 5]); B1 = cvtpk(sc0[R + 6], sc0[R + 7]);
      } else {
        A0 = cvtpk(sc1[R + 0], sc1[R + 1]); A1 = cvtpk(sc1[R + 2], sc1[R + 3]);
        B0 = cvtpk(sc1[R + 4], sc1[R + 5]); B1 = cvtpk(sc1[R + 6], sc1[R + 7]);
      }
      pl32swap(A0, B0);
      pl32swap(A1, B1);
      union { unsigned int w[4]; short8 v; } pa;
      pa.w[0] = A0; pa.w[1] = A1; pa.w[2] = B0; pa.w[3] = B1;
      short8 vf[4];
#pragma unroll
      for (int dc = 0; dc < 4; ++dc) {
        int row = dc * 32 + l31;
        int ss = (ks * 2 + hi) ^ (row & 7);
        vf[dc] = *reinterpret_cast<const short8*>((const char*)Vs + row * 128 + ss * 16);
      }
#pragma unroll
      for (int dc = 0; dc < 4; ++dc)
        o[dc] = mfma32(pa.v, vf[dc], o[dc]);
    }
    __builtin_amdgcn_s_setprio(0);

    __syncthreads();   // all waves done reading Vs before next-iter V staging
  }

  // ---- epilogue: divide by l (row stats at lane row), store bf16 ----
  float inv = 1.f / lrun;
#pragma unroll
  for (int r = 0; r < 16; ++r) {
    int qrow = (r & 3) + 8 * (r >> 2) + 4 * hi;
    float ir = __shfl(inv, qrow);
    long row = qb + qrow;
#pragma unroll
    for (int dc = 0; dc < 4; ++dc)
      AO[((long)b * SS + row) * KQ + h * HD + dc * 32 + l31] = f2bf(o[dc][r] * ir);
  }
}

// ---------- launch ----------
extern "C" void kernel_launch(void* const* d_in, const int* in_sizes, int n_in,
                              void* d_out, int out_size, void* d_ws, size_t ws_size,
                              hipStream_t stream) {
  const float* hidden = (const float*)d_in[0];
  const float* mask   = (const float*)d_in[1];
  const float* Wq     = (const float*)d_in[2];
  const float* Wk     = (const float*)d_in[3];
  const float* Wv     = (const float*)d_in[4];
  const float* Wo     = (const float*)d_in[5];

  char* ws = (char*)d_ws;
  constexpr long SZ_X   = (long)MM * HH * 2;          // 25.2 MB bf16
  constexpr long SZ_WQT = (long)HH * KQ * 2;          // 18.9 MB
  constexpr long SZ_WKT = (long)HH * KKV * 2;         // 6.3 MB
  constexpr long SZ_QKV = (long)MM * KKV * 2;         // 8.4 MB
  unsigned short* Xb  = (unsigned short*)(ws);
  unsigned short* WqT = (unsigned short*)(ws + SZ_X);
  unsigned short* WkT = (unsigned short*)(ws + SZ_X + SZ_WQT);
  unsigned short* WvT = (unsigned short*)(ws + SZ_X + SZ_WQT + SZ_WKT);
  unsigned short* WoT = (unsigned short*)(ws + SZ_X + SZ_WQT + 2 * SZ_WKT);
  unsigned short* Qb  = (unsigned short*)(ws + SZ_X + 2 * SZ_WQT + 2 * SZ_WKT);
  unsigned short* Kb  = (unsigned short*)(ws + 2 * SZ_X + 2 * SZ_WQT + 2 * SZ_WKT);
  unsigned short* Vb  = (unsigned short*)(ws + 2 * SZ_X + 2 * SZ_WQT + 2 * SZ_WKT + SZ_QKV);
  unsigned short* VTb = (unsigned short*)(ws + 2 * SZ_X + 2 * SZ_WQT + 2 * SZ_WKT + 2 * SZ_QKV);
  unsigned short* AOb = (unsigned short*)(ws + 2 * SZ_X + 2 * SZ_WQT + 2 * SZ_WKT + 3 * SZ_QKV);
  // mask bf16 (pre-scaled by log2e) reuses WqT region (dead after Q projection)
  unsigned short* Mbf = WqT;

  // 1) converts / weight transposes
  k_cvt<<<(MM * HH) / 1024, 256, 0, stream>>>(hidden, Xb, MM * HH, 1.0f);
  k_tcvt<<<dim3(KQ / 32, HH / 32), 256, 0, stream>>>(Wq, WqT, HH, KQ);
  k_tcvt<<<dim3(KKV / 32, HH / 32), 256, 0, stream>>>(Wk, WkT, HH, KKV);
  k_tcvt<<<dim3(KKV / 32, HH / 32), 256, 0, stream>>>(Wv, WvT, HH, KKV);
  k_tcvt<<<dim3(KQ / 32, HH / 32), 256, 0, stream>>>(Wo, WoT, KQ, HH);

  // 2) projections
  k_gemm<unsigned short><<<dim3(KQ / 128, MM / 128), 256, 0, stream>>>(Xb, WqT, Qb, MM, KQ, HH);
  k_gemm<unsigned short><<<dim3(KKV / 128, MM / 128), 256, 0, stream>>>(Xb, WkT, Kb, MM, KKV, HH);
  k_gemm<unsigned short><<<dim3(KKV / 128, MM / 128), 256, 0, stream>>>(Xb, WvT, Vb, MM, KKV, HH);

  // 3) V -> V^T ; mask fp32 -> bf16*log2e (overwrites WqT, now dead)
  k_vt<<<dim3(HD / 32, SS / 32, BB * NKV), 256, 0, stream>>>(Vb, VTb);
  k_cvt<<<(BB * SS * SS) / 1024, 256, 0, stream>>>(mask, Mbf, BB * SS * SS,
                                                   1.4426950408889634f);

  // 4) attention: 768 blocks x 4 waves, 3 blocks/CU, in-register softmax
  k_attn<<<16 * NH * BB, 256, 0, stream>>>(Qb, Kb, VTb, Mbf, AOb);

  // 5) output projection -> fp32 d_out
  k_gemm<float><<<dim3(HH / 128, MM / 128), 256, 0, stream>>>(AOb, WoT, (float*)d_out, MM, HH, HH);
}